// Round 12
// baseline (39.926 us; speedup 1.0000x reference)
//
#include <hip/hip_runtime.h>

// GSplat renderer, separable-Gaussian, LDS-resident accum + parallel reduce.
// R11 analysis: accum stuck at ~30us across 5 variants while issue models say
// ~12us; the shared parameter is 2 waves/SIMD (25% occ). This round isolates
// occupancy: NCHUNK 128->64 => LDS 25.8 KB => 6 blocks/CU = 6 waves/SIMD,
// same per-gaussian economics, same total work. parts=32 (partials 32 MB).
// Geometry: block = 64 cols x 32 rows, thread = 2 cols x 4 rows.

constexpr int HH = 256;
constexpr int WW = 256;
constexpr int PIX = HH * WW;
constexpr int NCHUNK = 64;
constexpr int CPB = 64;
constexpr int RPB = 32;
constexpr float COORD_STEP = 2.0f / 255.0f;

__device__ __forceinline__ unsigned bfr(float f) {  // f32 -> bf16 bits (RNE)
  unsigned u = __float_as_uint(f);
  return (u + 0x7fffu + ((u >> 16) & 1u)) >> 16;
}

__global__ __launch_bounds__(256, 6) void gs_accum(
    const float* __restrict__ means, const float* __restrict__ scales,
    const float* __restrict__ opac, const float* __restrict__ colors,
    float4* __restrict__ partials) {
  __shared__ float pxL[NCHUNK], pyL[NCHUNK], kL[NCHUNK];
  __shared__ float4 colL[NCHUNK];
  __shared__ float exL[NCHUNK][CPB];   // 16 KB
  __shared__ uint4 packL[NCHUNK][8];   // 8 KB  [g][rowgroup]

  const int t = threadIdx.x;
  const int n0 = blockIdx.z * NCHUNK;

  // --- per-gaussian params ---
  if (t < NCHUNK) {
    int n = n0 + t;
    float mx = means[3 * n], my = means[3 * n + 1], mz = means[3 * n + 2];
    float scl = fmaxf((scales[3 * n] + scales[3 * n + 1] + scales[3 * n + 2]) * (1.0f / 3.0f), 1e-4f);
    float op = opac[n];
    float rzs = 1.0f / (fabsf(mz) + 1.0f);
    float sigma = fminf(fmaxf(scl * rzs, 0.02f), 0.5f);
    float inv_s = 1.0f / sigma;
    pxL[t] = tanhf(mx * rzs);
    pyL[t] = tanhf(my * rzs);
    kL[t] = -0.72134752044f * inv_s * inv_s;  // -0.5/ln2 * inv_s^2
    colL[t] = make_float4(op * colors[3 * n], op * colors[3 * n + 1],
                          op * colors[3 * n + 2], op);
  }
  __syncthreads();

  // --- tables into LDS (absolute coords) ---
  {
    int c = t & 63;
    int jb = t >> 6;  // 0..3
    float ccol = -1.0f + COORD_STEP * (float)(blockIdx.x * CPB + c);
#pragma unroll 4
    for (int jj = 0; jj < NCHUNK / 4; ++jj) {
      int j = jb + (jj << 2);
      float dx = ccol - pxL[j];
      exL[j][c] = exp2f(kL[j] * dx * dx);
    }
#pragma unroll
    for (int k = 0; k < (NCHUNK * 8) / 256; ++k) {  // 2
      int e = t + (k << 8);
      int j = e >> 3;       // gaussian 0..63
      int rgf = e & 7;      // rowgroup 0..7
      int rb = blockIdx.y * RPB + (rgf << 2);
      float py = pyL[j], K = kL[j];
      float d0 = (-1.0f + COORD_STEP * (float)(rb + 0)) - py;
      float d1 = (-1.0f + COORD_STEP * (float)(rb + 1)) - py;
      float d2 = (-1.0f + COORD_STEP * (float)(rb + 2)) - py;
      float d3 = (-1.0f + COORD_STEP * (float)(rb + 3)) - py;
      float e0 = exp2f(K * d0 * d0);
      float e1 = exp2f(K * d1 * d1);
      float e2 = exp2f(K * d2 * d2);
      float e3 = exp2f(K * d3 * d3);
      float4 cv = colL[j];
      packL[j][rgf] = make_uint4(bfr(e0) | (bfr(e1) << 16),
                                 bfr(e2) | (bfr(e3) << 16),
                                 bfr(cv.x) | (bfr(cv.y) << 16),
                                 bfr(cv.z) | (bfr(cv.w) << 16));
    }
  }
  __syncthreads();

  // --- main contraction: 2 ds_reads per gaussian per wave ---
  const int c0 = (t & 31) << 1;   // local col pair
  const int rg = t >> 5;          // rowgroup 0..7 (4 rows)

  float4 a00 = make_float4(0.f, 0.f, 0.f, 0.f);
  float4 a01 = a00, a10 = a00, a11 = a00, a20 = a00, a21 = a00,
         a30 = a00, a31 = a00;

#pragma unroll 2
  for (int i = 0; i < NCHUNK; ++i) {
    float2 exv = *(const float2*)&exL[i][c0];
    uint4 pk = packL[i][rg];
    float ey0 = __uint_as_float(pk.x << 16);
    float ey1 = __uint_as_float(pk.x & 0xffff0000u);
    float ey2 = __uint_as_float(pk.y << 16);
    float ey3 = __uint_as_float(pk.y & 0xffff0000u);
    float crr = __uint_as_float(pk.z << 16);
    float cgg = __uint_as_float(pk.z & 0xffff0000u);
    float cbb = __uint_as_float(pk.w << 16);
    float cop = __uint_as_float(pk.w & 0xffff0000u);
#define GS_ROW(AR0, AR1, EY)                          \
    { float wA = (EY) * exv.x, wB = (EY) * exv.y;     \
      AR0.x = fmaf(wA, crr, AR0.x);                   \
      AR0.y = fmaf(wA, cgg, AR0.y);                   \
      AR0.z = fmaf(wA, cbb, AR0.z);                   \
      AR0.w = fmaf(wA, cop, AR0.w);                   \
      AR1.x = fmaf(wB, crr, AR1.x);                   \
      AR1.y = fmaf(wB, cgg, AR1.y);                   \
      AR1.z = fmaf(wB, cbb, AR1.z);                   \
      AR1.w = fmaf(wB, cop, AR1.w); }
    GS_ROW(a00, a01, ey0)
    GS_ROW(a10, a11, ey1)
    GS_ROW(a20, a21, ey2)
    GS_ROW(a30, a31, ey3)
#undef GS_ROW
  }

  // --- epilogue: pixel-major float4 (r,g,b,denom) ---
  float4* pb = partials + (size_t)blockIdx.z * PIX;
  int colabs = blockIdx.x * CPB + c0;
  int rowb = blockIdx.y * RPB + (rg << 2);
#define GS_ST(A0, A1, R)                              \
  { float4* rowp = pb + (rowb + (R)) * WW + colabs;   \
    rowp[0] = A0;                                     \
    rowp[1] = A1; }
  GS_ST(a00, a01, 0)
  GS_ST(a10, a11, 1)
  GS_ST(a20, a21, 2)
  GS_ST(a30, a31, 3)
#undef GS_ST
}

// grid = PIX/256 = 256 blocks; thread = one pixel; 32 independent b128 loads.
__global__ __launch_bounds__(256) void gs_finalize(
    const float4* __restrict__ partials, float* __restrict__ out,
    int parts) {
  int g = blockIdx.x * 256 + threadIdx.x;  // pixel id
  float sr = 0.f, sg = 0.f, sb = 0.f, sd = 0.f;
#pragma unroll 8
  for (int p = 0; p < parts; ++p) {
    float4 v = partials[(size_t)p * PIX + g];
    sr += v.x; sg += v.y; sb += v.z; sd += v.w;
  }
  float inv = 1.0f / fmaxf(sd, 1e-5f);
  out[0 * PIX + g] = fminf(fmaxf(sr * inv, 0.0f), 1.0f);
  out[1 * PIX + g] = fminf(fmaxf(sg * inv, 0.0f), 1.0f);
  out[2 * PIX + g] = fminf(fmaxf(sb * inv, 0.0f), 1.0f);
}

extern "C" void kernel_launch(void* const* d_in, const int* in_sizes, int n_in,
                              void* d_out, int out_size, void* d_ws, size_t ws_size,
                              hipStream_t stream) {
  const float* means = (const float*)d_in[0];
  // d_in[1] = quats (unused by reference)
  const float* scales = (const float*)d_in[2];
  const float* opac = (const float*)d_in[3];
  const float* colors = (const float*)d_in[4];
  float* out = (float*)d_out;
  int N = in_sizes[0] / 3;  // 2048

  int parts = N / NCHUNK;  // 32
  float4* partials = (float4*)d_ws;  // [parts][PIX] float4 = 32 MB

  gs_accum<<<dim3(WW / CPB, HH / RPB, parts), 256, 0, stream>>>(
      means, scales, opac, colors, partials);
  gs_finalize<<<PIX / 256, 256, 0, stream>>>(
      partials, out, parts);
}

// Round 14
// 34.460 us; speedup vs baseline: 1.1586x; 1.1586x over previous
//
#include <hip/hip_runtime.h>

// GSplat renderer, separable-Gaussian, LDS-resident accum + parallel reduce.
// R13 compile fix: v_pk_*_f32 operands must ALL be 64-bit VGPR pairs; the
// ey scalar is now one half of an f32x2, selected via op_sel broadcast.
// Lever under test (R12 theory): VALU-issue-bound -> packed f32 halves the
// FMA/mul issue slots (52 -> ~28 insts per gaussian per thread).
// Geometry = R11 (best): block 64x32 px, thread 2 cols x 4 rows,
// NCHUNK=128, parts=16, pixel-major float4 partials (16 MB).

constexpr int HH = 256;
constexpr int WW = 256;
constexpr int PIX = HH * WW;
constexpr int NCHUNK = 128;
constexpr int CPB = 64;
constexpr int RPB = 32;
constexpr float COORD_STEP = 2.0f / 255.0f;

typedef float f32x2 __attribute__((ext_vector_type(2)));

__device__ __forceinline__ unsigned bfr(float f) {  // f32 -> bf16 bits (RNE)
  unsigned u = __float_as_uint(f);
  return (u + 0x7fffu + ((u >> 16) & 1u)) >> 16;
}

// d = (s.lo * v.lo, s.lo * v.hi)  — s.lo broadcast via op_sel
__device__ __forceinline__ void pk_mul_blo(f32x2& d, f32x2 s, f32x2 v) {
  asm("v_pk_mul_f32 %0, %1, %2 op_sel:[0,0] op_sel_hi:[0,1]"
      : "=v"(d) : "v"(s), "v"(v));
}
// d = (s.hi * v.lo, s.hi * v.hi)
__device__ __forceinline__ void pk_mul_bhi(f32x2& d, f32x2 s, f32x2 v) {
  asm("v_pk_mul_f32 %0, %1, %2 op_sel:[1,0] op_sel_hi:[1,1]"
      : "=v"(d) : "v"(s), "v"(v));
}
// acc += w.lo * c   (w.lo broadcast to both halves)
__device__ __forceinline__ void pk_fma_lo(f32x2& acc, f32x2 w, f32x2 c) {
  asm("v_pk_fma_f32 %0, %1, %2, %0 op_sel:[0,0,0] op_sel_hi:[0,1,1]"
      : "+v"(acc) : "v"(w), "v"(c));
}
// acc += w.hi * c
__device__ __forceinline__ void pk_fma_hi(f32x2& acc, f32x2 w, f32x2 c) {
  asm("v_pk_fma_f32 %0, %1, %2, %0 op_sel:[1,0,0] op_sel_hi:[1,1,1]"
      : "+v"(acc) : "v"(w), "v"(c));
}

__global__ __launch_bounds__(256) void gs_accum(
    const float* __restrict__ means, const float* __restrict__ scales,
    const float* __restrict__ opac, const float* __restrict__ colors,
    float4* __restrict__ partials) {
  __shared__ float pxL[NCHUNK], pyL[NCHUNK], kL[NCHUNK];
  __shared__ float4 colL[NCHUNK];
  __shared__ float exL[NCHUNK][CPB];   // 32 KB
  __shared__ uint4 packL[NCHUNK][8];   // 16 KB  [g][rowgroup]

  const int t = threadIdx.x;
  const int n0 = blockIdx.z * NCHUNK;

  // --- per-gaussian params ---
  if (t < NCHUNK) {
    int n = n0 + t;
    float mx = means[3 * n], my = means[3 * n + 1], mz = means[3 * n + 2];
    float scl = fmaxf((scales[3 * n] + scales[3 * n + 1] + scales[3 * n + 2]) * (1.0f / 3.0f), 1e-4f);
    float op = opac[n];
    float rzs = 1.0f / (fabsf(mz) + 1.0f);
    float sigma = fminf(fmaxf(scl * rzs, 0.02f), 0.5f);
    float inv_s = 1.0f / sigma;
    pxL[t] = tanhf(mx * rzs);
    pyL[t] = tanhf(my * rzs);
    kL[t] = -0.72134752044f * inv_s * inv_s;  // -0.5/ln2 * inv_s^2
    colL[t] = make_float4(op * colors[3 * n], op * colors[3 * n + 1],
                          op * colors[3 * n + 2], op);
  }
  __syncthreads();

  // --- tables into LDS (absolute coords) ---
  {
    int c = t & 63;
    int jb = t >> 6;  // 0..3
    float ccol = -1.0f + COORD_STEP * (float)(blockIdx.x * CPB + c);
#pragma unroll 8
    for (int jj = 0; jj < NCHUNK / 4; ++jj) {
      int j = jb + (jj << 2);
      float dx = ccol - pxL[j];
      exL[j][c] = exp2f(kL[j] * dx * dx);
    }
#pragma unroll
    for (int k = 0; k < 4; ++k) {   // 1024 pack entries / 256 threads
      int e = t + (k << 8);
      int j = e >> 3;       // gaussian 0..127
      int rgf = e & 7;      // rowgroup 0..7
      int rb = blockIdx.y * RPB + (rgf << 2);
      float py = pyL[j], K = kL[j];
      float d0 = (-1.0f + COORD_STEP * (float)(rb + 0)) - py;
      float d1 = (-1.0f + COORD_STEP * (float)(rb + 1)) - py;
      float d2 = (-1.0f + COORD_STEP * (float)(rb + 2)) - py;
      float d3 = (-1.0f + COORD_STEP * (float)(rb + 3)) - py;
      float e0 = exp2f(K * d0 * d0);
      float e1 = exp2f(K * d1 * d1);
      float e2 = exp2f(K * d2 * d2);
      float e3 = exp2f(K * d3 * d3);
      float4 cv = colL[j];
      packL[j][rgf] = make_uint4(bfr(e0) | (bfr(e1) << 16),
                                 bfr(e2) | (bfr(e3) << 16),
                                 bfr(cv.x) | (bfr(cv.y) << 16),
                                 bfr(cv.z) | (bfr(cv.w) << 16));
    }
  }
  __syncthreads();

  // --- main contraction: 2 ds_reads + 4 pk_mul + 16 pk_fma per gaussian ---
  const int c0 = (t & 31) << 1;   // local col pair
  const int rg = t >> 5;          // rowgroup 0..7 (4 rows)

  // acc[row][colA/B][RG|BD]: 16 named f32x2 (32 VGPR)
  f32x2 z = {0.f, 0.f};
  f32x2 aRG_A0 = z, aBD_A0 = z, aRG_B0 = z, aBD_B0 = z;
  f32x2 aRG_A1 = z, aBD_A1 = z, aRG_B1 = z, aBD_B1 = z;
  f32x2 aRG_A2 = z, aBD_A2 = z, aRG_B2 = z, aBD_B2 = z;
  f32x2 aRG_A3 = z, aBD_A3 = z, aRG_B3 = z, aBD_B3 = z;

#pragma unroll 2
  for (int i = 0; i < NCHUNK; ++i) {
    f32x2 exv = *(const f32x2*)&exL[i][c0];
    uint4 pk = packL[i][rg];
    f32x2 ey01 = {__uint_as_float(pk.x << 16),
                  __uint_as_float(pk.x & 0xffff0000u)};
    f32x2 ey23 = {__uint_as_float(pk.y << 16),
                  __uint_as_float(pk.y & 0xffff0000u)};
    f32x2 cRG = {__uint_as_float(pk.z << 16),
                 __uint_as_float(pk.z & 0xffff0000u)};
    f32x2 cBD = {__uint_as_float(pk.w << 16),
                 __uint_as_float(pk.w & 0xffff0000u)};
    f32x2 w0, w1, w2, w3;
    pk_mul_blo(w0, ey01, exv);   // (ey0*exA, ey0*exB)
    pk_mul_bhi(w1, ey01, exv);
    pk_mul_blo(w2, ey23, exv);
    pk_mul_bhi(w3, ey23, exv);
    pk_fma_lo(aRG_A0, w0, cRG); pk_fma_lo(aBD_A0, w0, cBD);
    pk_fma_hi(aRG_B0, w0, cRG); pk_fma_hi(aBD_B0, w0, cBD);
    pk_fma_lo(aRG_A1, w1, cRG); pk_fma_lo(aBD_A1, w1, cBD);
    pk_fma_hi(aRG_B1, w1, cRG); pk_fma_hi(aBD_B1, w1, cBD);
    pk_fma_lo(aRG_A2, w2, cRG); pk_fma_lo(aBD_A2, w2, cBD);
    pk_fma_hi(aRG_B2, w2, cRG); pk_fma_hi(aBD_B2, w2, cBD);
    pk_fma_lo(aRG_A3, w3, cRG); pk_fma_lo(aBD_A3, w3, cBD);
    pk_fma_hi(aRG_B3, w3, cRG); pk_fma_hi(aBD_B3, w3, cBD);
  }

  // --- epilogue: pixel-major float4 (r,g,b,denom) ---
  float4* pb = partials + (size_t)blockIdx.z * PIX;
  int colabs = blockIdx.x * CPB + c0;
  int rowb = blockIdx.y * RPB + (rg << 2);
#define GS_ST(RG_A, BD_A, RG_B, BD_B, R)                          \
  { float4* rowp = pb + (rowb + (R)) * WW + colabs;               \
    rowp[0] = make_float4(RG_A.x, RG_A.y, BD_A.x, BD_A.y);        \
    rowp[1] = make_float4(RG_B.x, RG_B.y, BD_B.x, BD_B.y); }
  GS_ST(aRG_A0, aBD_A0, aRG_B0, aBD_B0, 0)
  GS_ST(aRG_A1, aBD_A1, aRG_B1, aBD_B1, 1)
  GS_ST(aRG_A2, aBD_A2, aRG_B2, aBD_B2, 2)
  GS_ST(aRG_A3, aBD_A3, aRG_B3, aBD_B3, 3)
#undef GS_ST
}

// grid = PIX/256 = 256 blocks; thread = one pixel; 16 independent b128 loads.
__global__ __launch_bounds__(256) void gs_finalize(
    const float4* __restrict__ partials, float* __restrict__ out,
    int parts) {
  int g = blockIdx.x * 256 + threadIdx.x;  // pixel id
  float sr = 0.f, sg = 0.f, sb = 0.f, sd = 0.f;
#pragma unroll 16
  for (int p = 0; p < parts; ++p) {
    float4 v = partials[(size_t)p * PIX + g];
    sr += v.x; sg += v.y; sb += v.z; sd += v.w;
  }
  float inv = 1.0f / fmaxf(sd, 1e-5f);
  out[0 * PIX + g] = fminf(fmaxf(sr * inv, 0.0f), 1.0f);
  out[1 * PIX + g] = fminf(fmaxf(sg * inv, 0.0f), 1.0f);
  out[2 * PIX + g] = fminf(fmaxf(sb * inv, 0.0f), 1.0f);
}

extern "C" void kernel_launch(void* const* d_in, const int* in_sizes, int n_in,
                              void* d_out, int out_size, void* d_ws, size_t ws_size,
                              hipStream_t stream) {
  const float* means = (const float*)d_in[0];
  // d_in[1] = quats (unused by reference)
  const float* scales = (const float*)d_in[2];
  const float* opac = (const float*)d_in[3];
  const float* colors = (const float*)d_in[4];
  float* out = (float*)d_out;
  int N = in_sizes[0] / 3;  // 2048

  int parts = N / NCHUNK;  // 16
  float4* partials = (float4*)d_ws;  // [parts][PIX] float4 = 16 MB

  gs_accum<<<dim3(WW / CPB, HH / RPB, parts), 256, 0, stream>>>(
      means, scales, opac, colors, partials);
  gs_finalize<<<PIX / 256, 256, 0, stream>>>(
      partials, out, parts);
}